// Round 16
// baseline (85.539 us; speedup 1.0000x reference)
//
#include <hip/hip_runtime.h>
#include <hip/hip_bf16.h>

#define NB 4
#define CIN 64
#define COUT 64
#define HH 128
#define WW 128
#define HW (HH*WW)
#define C_OFF 144
#define C_OM 216
#define C_PAD 224
#define KTOT 576   // CIN * 9

typedef __attribute__((ext_vector_type(8))) short bf16x8;
typedef __attribute__((ext_vector_type(4))) float f32x4;
typedef __attribute__((ext_vector_type(8))) unsigned short uv8;

__device__ inline unsigned short f2bf(float f) {
    union { float f; unsigned u; } v; v.f = f;
    unsigned r = (v.u + 0x7FFF + ((v.u >> 16) & 1)) >> 16;   // RNE
    return (unsigned short)r;
}

__device__ inline float bf2f(unsigned short h) {
    union { unsigned u; float f; } v; v.u = ((unsigned)h) << 16; return v.f;
}

// ---------------- prep kernels (validated) ----------------

__global__ __launch_bounds__(256) void transpose_wdcn(const float* __restrict__ w,
                                                      float* __restrict__ wT) {
    int idx = blockIdx.x * 256 + threadIdx.x;
    if (idx < KTOT * COUT) {
        int o = idx & 63, kk = idx >> 6;
        wT[idx] = w[o * KTOT + kk];
    }
}

// merged: [b][c][y][x] f32 -> [b][y][x][c] bf16 for BOTH feature and input (R12-validated)
__global__ __launch_bounds__(256) void to_nhwc_bf16_2(const float* __restrict__ f0,
                                                      unsigned short* __restrict__ o0,
                                                      const float* __restrict__ f1,
                                                      unsigned short* __restrict__ o1) {
    int t = blockIdx.x * 256 + threadIdx.x;      // 0..131071
    const float* src;
    unsigned short* dst;
    int tt = t & 65535;
    int b = tt >> 14, yx = tt & 16383;
    if (t < 65536) { src = f0 + (size_t)b * CIN * HW + yx; dst = o0 + (size_t)tt * 64; }
    else           { src = f1 + (size_t)b * CIN * HW + yx; dst = o1 + (size_t)tt * 64; }
#pragma unroll
    for (int c8 = 0; c8 < 8; ++c8) {
        uv8 v;
#pragma unroll
        for (int j = 0; j < 8; ++j) v[j] = f2bf(src[(size_t)(c8 * 8 + j) * HW]);
        *(uv8*)(dst + c8 * 8) = v;
    }
}

// merged weight prep: wB (224*576) then wTf2 (72*64*8); formulas verbatim R10
__global__ __launch_bounds__(256) void prep_weights(const float* __restrict__ w_off,
                                                    const float* __restrict__ w_mask,
                                                    const float* __restrict__ w_dcn,
                                                    unsigned short* __restrict__ wB,
                                                    unsigned short* __restrict__ wTf2) {
    int idx = blockIdx.x * 256 + threadIdx.x;
    if (idx < C_PAD * KTOT) {
        int co = idx / KTOT, k = idx - co * KTOT;
        int t = k >> 6, ci = k & 63;
        float v = 0.f;
        if (co < C_OFF)      v = w_off[(size_t)co * KTOT + ci * 9 + t];
        else if (co < C_OM)  v = w_mask[(size_t)(co - C_OFF) * KTOT + ci * 9 + t];
        wB[idx] = f2bf(v);
    } else if (idx < C_PAD * KTOT + 72 * 64 * 8) {
        int j = idx - C_PAD * KTOT;
        int q = j >> 9;
        int co = (j >> 3) & 63;
        int r = j & 7;
        int k = q >> 3, dg = q & 7;
        wTf2[j] = f2bf(w_dcn[(size_t)co * KTOT + (dg * 8 + r) * 9 + k]);
    }
}

// ---------------- fused: conv(B-reuse supertile) -> om_l -> sampling -> dot ----------------
// R15-validated kernel (best known: 84.4us, XCD swizzle). Single change this
// round: conv B-staging uses __builtin_amdgcn_global_load_lds (16B DMA) with a
// LINEAR LDS dest (lane-stride-16) and a PRE-SWIZZLED global source
// (c8e = c8 ^ (co&7)), per rule #21 — LDS content is byte-identical to R15,
// so the MFMA read side (XOR pattern, bank behavior) is untouched.
// A-staging keeps the guarded register path (border zero-fill).

__global__ __launch_bounds__(256, 4) void dcn_fused(
    const unsigned short* __restrict__ fnhwc,  // feature NHWC bf16
    const unsigned short* __restrict__ inb,    // input NHWC bf16
    const unsigned short* __restrict__ wB,     // [224][576] bf16
    const unsigned short* __restrict__ wTf2,   // [72][64][8] bf16
    const float* __restrict__ b_off, const float* __restrict__ b_mask,
    const float* __restrict__ b_dcn,
    float* __restrict__ out)
{
    __shared__ __align__(16) unsigned char smem[36864];   // arena
    unsigned short* Ash0  = (unsigned short*)smem;              // [0,4096)
    unsigned short* Ash1  = (unsigned short*)(smem + 4096);     // [4096,8192)
    unsigned short* Bsh   = (unsigned short*)(smem + 8192);     // [8192,36864)
    float* om_l           = (float*)smem;                       // [0,29568)
    unsigned short* val_q = (unsigned short*)smem;              // [0,36864)

    int tid = threadIdx.x;
    int bid0 = blockIdx.x;                // 1024
    int bid  = ((bid0 & 7) << 7) + (bid0 >> 3);   // T1: XCD gets 128 consecutive supertiles
    int b   = bid >> 8;
    int hw0 = (bid & 255) << 6;           // 64-px supertile, row-aligned
    int ho  = hw0 >> 7;
    int wo0 = hw0 & 127;                  // 0 or 64

    int lane = tid & 63, wave = tid >> 6;
    int arow = lane & 15, g = lane >> 4;
    int h  = wave & 1;                    // px 16-half within 32-px tile
    int ws = wave >> 1;                   // co 112-half

    // ---- conv phase ----
    f32x4 acc0[7], acc1[7];
#pragma unroll
    for (int n = 0; n < 7; ++n) {
        acc0[n] = (f32x4){0.f, 0.f, 0.f, 0.f};
        acc1[n] = (f32x4){0.f, 0.f, 0.f, 0.f};
    }

    int px_w = tid >> 3;                  // 0..31
    int c8_w = tid & 7;
    const uv8 zero8 = (uv8){0, 0, 0, 0, 0, 0, 0, 0};

    for (int t = 0; t < 9; ++t) {
        int ky = t / 3, kx = t - ky * 3;
        int y = ho + ky - 1;
        bool yv = (unsigned)y < (unsigned)HH;
        __syncthreads();
        // stage A for both px tiles (R10 swizzle, guarded reg path: border zero-fill)
#pragma unroll
        for (int pt = 0; pt < 2; ++pt) {
            int x = wo0 + pt * 32 + px_w + kx - 1;
            uv8 v = zero8;
            if (yv && (unsigned)x < (unsigned)WW)
                v = *(const uv8*)(fnhwc + ((size_t)((b * HH + y) * WW + x) << 6) + c8_w * 8);
            int off16 = (c8_w << 4) ^ ((px_w & 7) << 4);
            char* dst = (char*)(pt ? Ash1 : Ash0);
            *(uv8*)(dst + px_w * 128 + off16) = v;
        }
        // stage B tile for this tap: async 16B global->LDS DMA.
        // Linear dest Bsh + idx*16 (= co*128 + c8*16, lane-stride-16 per wave);
        // source chunk pre-swizzled c8e = c8 ^ (co&7) so LDS content matches
        // the R15 swizzled layout exactly (read side unchanged).
#pragma unroll
        for (int r = 0; r < 7; ++r) {
            int idx = r * 256 + tid;      // 0..1791 = 224*8 chunks
            int co = idx >> 3, c8 = idx & 7;
            int c8e = c8 ^ (co & 7);
            __builtin_amdgcn_global_load_lds(
                (__attribute__((address_space(1))) void*)(
                    (void*)(wB + (size_t)co * KTOT + t * 64 + c8e * 8)),
                (__attribute__((address_space(3))) void*)((char*)Bsh + idx * 16),
                16, 0, 0);
        }
        __syncthreads();
#pragma unroll
        for (int half = 0; half < 2; ++half) {
            int px = h * 16 + arow;
            int kb = half * 64 + g * 16;
            bf16x8 a0 = *(const bf16x8*)((const char*)Ash0 + px * 128 + (kb ^ ((px & 7) << 4)));
            bf16x8 a1 = *(const bf16x8*)((const char*)Ash1 + px * 128 + (kb ^ ((px & 7) << 4)));
#pragma unroll
            for (int n = 0; n < 7; ++n) {
                int co = ws * 112 + n * 16 + arow;   // co&7 == arow&7
                bf16x8 bf = *(const bf16x8*)((const char*)Bsh + co * 128 +
                                             (kb ^ ((co & 7) << 4)));
                acc0[n] = __builtin_amdgcn_mfma_f32_16x16x32_bf16(a0, bf, acc0[n], 0, 0, 0);
                acc1[n] = __builtin_amdgcn_mfma_f32_16x16x32_bf16(a1, bf, acc1[n], 0, 0, 0);
            }
        }
    }
    __syncthreads();   // all Ash/Bsh reads done before om_l overwrites the arena

    // ---- post-conv phases, per 32-px tile (verbatim R10 each) ----
#pragma unroll
    for (int pt = 0; pt < 2; ++pt) {
        int hw0t = hw0 + pt * 32;
        int wo0t = wo0 + pt * 32;

        // conv epilogue -> om_l (bias + sigmoid for mask channels)
#pragma unroll
        for (int n = 0; n < 7; ++n) {
            int co = ws * 112 + n * 16 + arow;
            if (co < C_OM) {
                float bias = (co < C_OFF) ? b_off[co] : b_mask[co - C_OFF];
                f32x4 av = pt ? acc1[n] : acc0[n];
#pragma unroll
                for (int j = 0; j < 4; ++j) {
                    float v = av[j] + bias;
                    if (co >= C_OFF) v = 1.f / (1.f + __expf(-v));
                    om_l[co * 33 + h * 16 + g * 4 + j] = v;
                }
            }
        }
        __syncthreads();

        // om -> registers (before val_q overwrites the arena)
        int px = tid & 31;
        int dg = tid >> 5;                // 0..7

        float dy[9], dxv[9], mk[9];
#pragma unroll
        for (int k = 0; k < 9; ++k) {
            dy[k]  = om_l[(dg * 18 + 2 * k) * 33 + px];
            dxv[k] = om_l[(dg * 18 + 2 * k + 1) * 33 + px];
            mk[k]  = om_l[(C_OFF + dg * 9 + k) * 33 + px];
        }
        __syncthreads();                  // om_l reads complete; arena may be reused

        // sampling phase
        const unsigned short* plane0 = inb + ((size_t)b * HW << 6) + dg * 8;
        float yb = (float)(ho - 1);
        float xb = (float)(wo0t + px - 1);

#pragma unroll
        for (int k = 0; k < 9; ++k) {
            float ys = dy[k] + yb + (float)(k / 3);
            float xs = dxv[k] + xb + (float)(k % 3);
            float y0f = floorf(ys), x0f = floorf(xs);
            float fy = ys - y0f, fx = xs - x0f;
            int y0 = (int)y0f, x0 = (int)x0f;
            bool yv0 = (unsigned)y0 < (unsigned)HH;
            bool yv1 = (unsigned)(y0 + 1) < (unsigned)HH;
            bool xv0 = (unsigned)x0 < (unsigned)WW;
            bool xv1 = (unsigned)(x0 + 1) < (unsigned)WW;
            const unsigned short* pp = plane0 + (y0 * WW + x0) * 64;
            uv8 c00 = zero8, c01 = zero8, c10 = zero8, c11 = zero8;
            if (yv0 && xv0) c00 = *(const uv8*)(pp);
            if (yv0 && xv1) c01 = *(const uv8*)(pp + 64);
            if (yv1 && xv0) c10 = *(const uv8*)(pp + 64 * WW);
            if (yv1 && xv1) c11 = *(const uv8*)(pp + 64 * WW + 64);
            uv8 r;
#pragma unroll
            for (int j = 0; j < 8; ++j) {
                float v00 = bf2f(c00[j]), v01 = bf2f(c01[j]);
                float v10 = bf2f(c10[j]), v11 = bf2f(c11[j]);
                float top = v00 + (v01 - v00) * fx;
                float bot = v10 + (v11 - v10) * fx;
                float v = top + (bot - top) * fy;
                r[j] = f2bf(v * mk[k]);
            }
            *(uv8*)(val_q + (k * 8 + dg) * 256 + px * 8) = r;
        }
        __syncthreads();

        // dot phase
        int nh = wave >> 1;

        f32x4 dacc[2];
        dacc[0] = dacc[1] = (f32x4){0.f, 0.f, 0.f, 0.f};
#pragma unroll
        for (int s = 0; s < 18; ++s) {
            int q = s * 4 + g;
            bf16x8 a = *(const bf16x8*)(val_q + q * 256 + (h * 16 + arow) * 8);
#pragma unroll
            for (int n = 0; n < 2; ++n) {
                int co = nh * 32 + n * 16 + arow;
                bf16x8 bfr = *(const bf16x8*)(wTf2 + ((size_t)q * 64 + co) * 8);
                dacc[n] = __builtin_amdgcn_mfma_f32_16x16x32_bf16(a, bfr, dacc[n], 0, 0, 0);
            }
        }

#pragma unroll
        for (int n = 0; n < 2; ++n) {
            int co = nh * 32 + n * 16 + arow;
            float bias = b_dcn[co];
            f32x4 r;
#pragma unroll
            for (int j = 0; j < 4; ++j) r[j] = dacc[n][j] + bias;
            *(f32x4*)(out + (size_t)b * COUT * HW + (size_t)co * HW + hw0t + h * 16 + g * 4) = r;
        }
        __syncthreads();                  // dot reads done before next tile's epilogue
    }
}

// ---------------- fallback f32 kernels (if ws too small) ----------------

__global__ __launch_bounds__(256) void conv_om_kernel(
    const float* __restrict__ feature,
    const float* __restrict__ w_off, const float* __restrict__ b_off,
    const float* __restrict__ w_mask, const float* __restrict__ b_mask,
    float* __restrict__ om)
{
    int tid = threadIdx.x;
    int p = blockIdx.x * 256 + tid;
    int cg = blockIdx.y;
    int b  = p >> 14;
    int hw = p & (HW - 1);
    int ho = hw >> 7;
    int wo = hw & 127;
    int co0 = cg * 4;

    float acc[4];
    const float* wb[4];
#pragma unroll
    for (int j = 0; j < 4; ++j) {
        int co = co0 + j;
        if (co < C_OFF) { acc[j] = b_off[co];          wb[j] = w_off  + (size_t)co * 576; }
        else            { acc[j] = b_mask[co - C_OFF]; wb[j] = w_mask + (size_t)(co - C_OFF) * 576; }
    }
    const float* fb = feature + (size_t)b * CIN * HW;
    for (int ci = 0; ci < CIN; ++ci) {
        const float* fp = fb + ci * HW;
#pragma unroll
        for (int ky = 0; ky < 3; ++ky) {
            int y = ho + ky - 1;
            bool yvb = (unsigned)y < (unsigned)HH;
#pragma unroll
            for (int kx = 0; kx < 3; ++kx) {
                int x = wo + kx - 1;
                float v = (yvb && (unsigned)x < (unsigned)WW) ? fp[y * WW + x] : 0.f;
                int wi = ci * 9 + ky * 3 + kx;
#pragma unroll
                for (int j = 0; j < 4; ++j) acc[j] += v * wb[j][wi];
            }
        }
    }
    size_t obase = (size_t)b * C_OM * HW + hw;
#pragma unroll
    for (int j = 0; j < 4; ++j) {
        int co = co0 + j;
        float v = acc[j];
        if (co >= C_OFF) v = 1.f / (1.f + __expf(-v));
        om[obase + (size_t)co * HW] = v;
    }
}

__global__ __launch_bounds__(256) void dcn_kernel(
    const float* __restrict__ input,
    const float* __restrict__ om,
    const float* __restrict__ wT,
    const float* __restrict__ b_dcn,
    float* __restrict__ out)
{
    __shared__ float om_l[C_OM * 16];
    __shared__ float val_l[KTOT * 16];

    int tid  = threadIdx.x;
    int tile = blockIdx.x;
    int b    = tile >> 10;
    int hw0  = (tile & 1023) << 4;
    int ho   = hw0 >> 7;
    int wo0  = hw0 & 127;

    const float* omg = om + (size_t)b * C_OM * HW + hw0;
    for (int i = tid; i < C_OM * 16; i += 256) {
        int ch = i >> 4, px = i & 15;
        om_l[i] = omg[(size_t)ch * HW + px];
    }
    __syncthreads();

    for (int pair = tid; pair < 1024; pair += 256) {
        int px = pair & 15, c = pair >> 4;
        int dg = c >> 3;
        const float* plane = input + (size_t)(b * CIN + c) * HW;
        float yb = (float)(ho - 1);
        float xb = (float)(wo0 + px - 1);
#pragma unroll
        for (int k = 0; k < 9; ++k) {
            float dyv = om_l[(dg * 18 + 2 * k) * 16 + px];
            float dxv = om_l[(dg * 18 + 2 * k + 1) * 16 + px];
            float m  = om_l[(C_OFF + dg * 9 + k) * 16 + px];
            float ys = dyv + yb + (float)(k / 3);
            float xs = dxv + xb + (float)(k % 3);
            float y0f = floorf(ys), x0f = floorf(xs);
            float wy = ys - y0f, wx = xs - x0f;
            int y0 = (int)y0f, x0 = (int)x0f;
            bool yv0 = (unsigned)y0 < (unsigned)HH;
            bool yv1 = (unsigned)(y0 + 1) < (unsigned)HH;
            bool xv0 = (unsigned)x0 < (unsigned)WW;
            bool xv1 = (unsigned)(x0 + 1) < (unsigned)WW;
            const float* r0 = plane + y0 * WW + x0;
            float v00 = (yv0 && xv0) ? r0[0]      : 0.f;
            float v01 = (yv0 && xv1) ? r0[1]      : 0.f;
            float v10 = (yv1 && xv0) ? r0[WW]     : 0.f;
            float v11 = (yv1 && xv1) ? r0[WW + 1] : 0.f;
            float top = v00 + (v01 - v00) * wx;
            float bot = v10 + (v11 - v10) * wx;
            float v = top + (bot - top) * wy;
            val_l[(c * 9 + k) * 16 + px] = v * m;
        }
    }
    __syncthreads();

    int o2 = tid & 31;
    int ph = tid >> 5;
    int o0 = o2 * 2, px0 = ph * 2;
    float a00 = b_dcn[o0],     a01 = b_dcn[o0];
    float a10 = b_dcn[o0 + 1], a11 = b_dcn[o0 + 1];
    for (int kk = 0; kk < KTOT; ++kk) {
        float2 wv = *reinterpret_cast<const float2*>(wT + kk * 64 + o0);
        float va = val_l[kk * 16 + px0];
        float vb = val_l[kk * 16 + px0 + 1];
        a00 += wv.x * va; a01 += wv.x * vb;
        a10 += wv.y * va; a11 += wv.y * vb;
    }
    float* ob = out + (size_t)b * COUT * HW + hw0;
    ob[(size_t)o0 * HW + px0]           = a00;
    ob[(size_t)o0 * HW + px0 + 1]       = a01;
    ob[(size_t)(o0 + 1) * HW + px0]     = a10;
    ob[(size_t)(o0 + 1) * HW + px0 + 1] = a11;
}

extern "C" void kernel_launch(void* const* d_in, const int* in_sizes, int n_in,
                              void* d_out, int out_size, void* d_ws, size_t ws_size,
                              hipStream_t stream) {
    const float* input   = (const float*)d_in[0];
    const float* feature = (const float*)d_in[1];
    const float* w_off   = (const float*)d_in[2];
    const float* b_off   = (const float*)d_in[3];
    const float* w_mask  = (const float*)d_in[4];
    const float* b_mask  = (const float*)d_in[5];
    const float* w_dcn   = (const float*)d_in[6];
    const float* b_dcn   = (const float*)d_in[7];
    float* out = (float*)d_out;

    // ws layout (full path): no om buffer needed
    unsigned short* fnhwc = (unsigned short*)d_ws;                   // 8.39 MB
    unsigned short* wBp   = fnhwc + (size_t)NB * HW * CIN;           // 258 KB
    unsigned short* wTfp  = wBp + (size_t)C_PAD * KTOT;              // 73.7 KB
    unsigned short* inb   = wTfp + 72 * 64 * 8;                      // 8.39 MB
    size_t need_full = (size_t)((char*)(inb + (size_t)NB * HW * CIN) - (char*)d_ws);
    // fallback needs om (56.6 MB) + wT (147 KB)
    size_t need_fb = ((size_t)NB * C_OM * HW + KTOT * COUT) * sizeof(float);

    if (ws_size >= need_full) {
        to_nhwc_bf16_2<<<NB * HW * 2 / 256, 256, 0, stream>>>(feature, fnhwc, input, inb);
        prep_weights<<<(C_PAD * KTOT + 72 * 64 * 8 + 255) / 256, 256, 0, stream>>>(
            w_off, w_mask, w_dcn, wBp, wTfp);
        dcn_fused<<<NB * HW / 64, 256, 0, stream>>>(fnhwc, inb, wBp, wTfp,
                                                    b_off, b_mask, b_dcn, out);
    } else if (ws_size >= need_fb) {
        // fallback: pure f32 path (R1-validated)
        float* om = (float*)d_ws;
        float* wT = om + (size_t)NB * C_OM * HW;
        transpose_wdcn<<<(KTOT * COUT + 255) / 256, 256, 0, stream>>>(w_dcn, wT);
        dim3 cgrid(NB * HW / 256, 54);
        conv_om_kernel<<<cgrid, 256, 0, stream>>>(feature, w_off, b_off, w_mask, b_mask, om);
        dcn_kernel<<<NB * HW / 16, 256, 0, stream>>>(input, om, wT, b_dcn, out);
    }
}

// Round 17
// 85.148 us; speedup vs baseline: 1.0046x; 1.0046x over previous
//
#include <hip/hip_runtime.h>
#include <hip/hip_bf16.h>

#define NB 4
#define CIN 64
#define COUT 64
#define HH 128
#define WW 128
#define HW (HH*WW)
#define C_OFF 144
#define C_OM 216
#define C_PAD 224
#define KTOT 576   // CIN * 9

typedef __attribute__((ext_vector_type(8))) short bf16x8;
typedef __attribute__((ext_vector_type(4))) float f32x4;
typedef __attribute__((ext_vector_type(8))) unsigned short uv8;

__device__ inline unsigned short f2bf(float f) {
    union { float f; unsigned u; } v; v.f = f;
    unsigned r = (v.u + 0x7FFF + ((v.u >> 16) & 1)) >> 16;   // RNE
    return (unsigned short)r;
}

__device__ inline float bf2f(unsigned short h) {
    union { unsigned u; float f; } v; v.u = ((unsigned)h) << 16; return v.f;
}

// ---------------- prep kernels (validated) ----------------

__global__ __launch_bounds__(256) void transpose_wdcn(const float* __restrict__ w,
                                                      float* __restrict__ wT) {
    int idx = blockIdx.x * 256 + threadIdx.x;
    if (idx < KTOT * COUT) {
        int o = idx & 63, kk = idx >> 6;
        wT[idx] = w[o * KTOT + kk];
    }
}

// merged: [b][c][y][x] f32 -> [b][y][x][c] bf16 for BOTH feature and input (R12-validated)
__global__ __launch_bounds__(256) void to_nhwc_bf16_2(const float* __restrict__ f0,
                                                      unsigned short* __restrict__ o0,
                                                      const float* __restrict__ f1,
                                                      unsigned short* __restrict__ o1) {
    int t = blockIdx.x * 256 + threadIdx.x;      // 0..131071
    const float* src;
    unsigned short* dst;
    int tt = t & 65535;
    int b = tt >> 14, yx = tt & 16383;
    if (t < 65536) { src = f0 + (size_t)b * CIN * HW + yx; dst = o0 + (size_t)tt * 64; }
    else           { src = f1 + (size_t)b * CIN * HW + yx; dst = o1 + (size_t)tt * 64; }
#pragma unroll
    for (int c8 = 0; c8 < 8; ++c8) {
        uv8 v;
#pragma unroll
        for (int j = 0; j < 8; ++j) v[j] = f2bf(src[(size_t)(c8 * 8 + j) * HW]);
        *(uv8*)(dst + c8 * 8) = v;
    }
}

// merged weight prep: wB (224*576) then wTf2 (72*64*8); formulas verbatim R10
__global__ __launch_bounds__(256) void prep_weights(const float* __restrict__ w_off,
                                                    const float* __restrict__ w_mask,
                                                    const float* __restrict__ w_dcn,
                                                    unsigned short* __restrict__ wB,
                                                    unsigned short* __restrict__ wTf2) {
    int idx = blockIdx.x * 256 + threadIdx.x;
    if (idx < C_PAD * KTOT) {
        int co = idx / KTOT, k = idx - co * KTOT;
        int t = k >> 6, ci = k & 63;
        float v = 0.f;
        if (co < C_OFF)      v = w_off[(size_t)co * KTOT + ci * 9 + t];
        else if (co < C_OM)  v = w_mask[(size_t)(co - C_OFF) * KTOT + ci * 9 + t];
        wB[idx] = f2bf(v);
    } else if (idx < C_PAD * KTOT + 72 * 64 * 8) {
        int j = idx - C_PAD * KTOT;
        int q = j >> 9;
        int co = (j >> 3) & 63;
        int r = j & 7;
        int k = q >> 3, dg = q & 7;
        wTf2[j] = f2bf(w_dcn[(size_t)co * KTOT + (dg * 8 + r) * 9 + k]);
    }
}

// ---------------- fused: conv(B-reuse supertile) -> om_l -> sampling -> dot ----------------
// R15-validated kernel (best known: 84.4us; XCD swizzle; reg-path B staging —
// R16's global_load_lds was neutral, reverted). Single change vs R15: the
// sampling loop processes taps in PAIRS — both taps' 8 corner loads issue
// before either tap's interpolation (2x gather MLP). Same loads, same values,
// same val_q write order => bit-identical output. Register budget audited:
// peak live ~110 < 128 cap (pairs, not triples, per R14's spill lesson).

__global__ __launch_bounds__(256, 4) void dcn_fused(
    const unsigned short* __restrict__ fnhwc,  // feature NHWC bf16
    const unsigned short* __restrict__ inb,    // input NHWC bf16
    const unsigned short* __restrict__ wB,     // [224][576] bf16
    const unsigned short* __restrict__ wTf2,   // [72][64][8] bf16
    const float* __restrict__ b_off, const float* __restrict__ b_mask,
    const float* __restrict__ b_dcn,
    float* __restrict__ out)
{
    __shared__ __align__(16) unsigned char smem[36864];   // arena
    unsigned short* Ash0  = (unsigned short*)smem;              // [0,4096)
    unsigned short* Ash1  = (unsigned short*)(smem + 4096);     // [4096,8192)
    unsigned short* Bsh   = (unsigned short*)(smem + 8192);     // [8192,36864)
    float* om_l           = (float*)smem;                       // [0,29568)
    unsigned short* val_q = (unsigned short*)smem;              // [0,36864)

    int tid = threadIdx.x;
    int bid0 = blockIdx.x;                // 1024
    int bid  = ((bid0 & 7) << 7) + (bid0 >> 3);   // T1: XCD gets 128 consecutive supertiles
    int b   = bid >> 8;
    int hw0 = (bid & 255) << 6;           // 64-px supertile, row-aligned
    int ho  = hw0 >> 7;
    int wo0 = hw0 & 127;                  // 0 or 64

    int lane = tid & 63, wave = tid >> 6;
    int arow = lane & 15, g = lane >> 4;
    int h  = wave & 1;                    // px 16-half within 32-px tile
    int ws = wave >> 1;                   // co 112-half

    // ---- conv phase ----
    f32x4 acc0[7], acc1[7];
#pragma unroll
    for (int n = 0; n < 7; ++n) {
        acc0[n] = (f32x4){0.f, 0.f, 0.f, 0.f};
        acc1[n] = (f32x4){0.f, 0.f, 0.f, 0.f};
    }

    int px_w = tid >> 3;                  // 0..31
    int c8_w = tid & 7;
    const uv8 zero8 = (uv8){0, 0, 0, 0, 0, 0, 0, 0};

    for (int t = 0; t < 9; ++t) {
        int ky = t / 3, kx = t - ky * 3;
        int y = ho + ky - 1;
        bool yv = (unsigned)y < (unsigned)HH;
        __syncthreads();
        // stage A for both px tiles (R10 swizzle)
#pragma unroll
        for (int pt = 0; pt < 2; ++pt) {
            int x = wo0 + pt * 32 + px_w + kx - 1;
            uv8 v = zero8;
            if (yv && (unsigned)x < (unsigned)WW)
                v = *(const uv8*)(fnhwc + ((size_t)((b * HH + y) * WW + x) << 6) + c8_w * 8);
            int off16 = (c8_w << 4) ^ ((px_w & 7) << 4);
            char* dst = (char*)(pt ? Ash1 : Ash0);
            *(uv8*)(dst + px_w * 128 + off16) = v;
        }
        // stage B tile for this tap (R10 swizzle), shared by both px tiles
#pragma unroll
        for (int r = 0; r < 7; ++r) {
            int idx = r * 256 + tid;      // 0..1791 = 224*8 chunks
            int co = idx >> 3, c8 = idx & 7;
            uv8 v = *(const uv8*)(wB + (size_t)co * KTOT + t * 64 + c8 * 8);
            *(uv8*)((char*)Bsh + co * 128 + ((c8 << 4) ^ ((co & 7) << 4))) = v;
        }
        __syncthreads();
#pragma unroll
        for (int half = 0; half < 2; ++half) {
            int px = h * 16 + arow;
            int kb = half * 64 + g * 16;
            bf16x8 a0 = *(const bf16x8*)((const char*)Ash0 + px * 128 + (kb ^ ((px & 7) << 4)));
            bf16x8 a1 = *(const bf16x8*)((const char*)Ash1 + px * 128 + (kb ^ ((px & 7) << 4)));
#pragma unroll
            for (int n = 0; n < 7; ++n) {
                int co = ws * 112 + n * 16 + arow;   // co&7 == arow&7
                bf16x8 bf = *(const bf16x8*)((const char*)Bsh + co * 128 +
                                             (kb ^ ((co & 7) << 4)));
                acc0[n] = __builtin_amdgcn_mfma_f32_16x16x32_bf16(a0, bf, acc0[n], 0, 0, 0);
                acc1[n] = __builtin_amdgcn_mfma_f32_16x16x32_bf16(a1, bf, acc1[n], 0, 0, 0);
            }
        }
    }
    __syncthreads();   // all Ash/Bsh reads done before om_l overwrites the arena

    // ---- post-conv phases, per 32-px tile ----
#pragma unroll
    for (int pt = 0; pt < 2; ++pt) {
        int hw0t = hw0 + pt * 32;
        int wo0t = wo0 + pt * 32;

        // conv epilogue -> om_l (bias + sigmoid for mask channels)
#pragma unroll
        for (int n = 0; n < 7; ++n) {
            int co = ws * 112 + n * 16 + arow;
            if (co < C_OM) {
                float bias = (co < C_OFF) ? b_off[co] : b_mask[co - C_OFF];
                f32x4 av = pt ? acc1[n] : acc0[n];
#pragma unroll
                for (int j = 0; j < 4; ++j) {
                    float v = av[j] + bias;
                    if (co >= C_OFF) v = 1.f / (1.f + __expf(-v));
                    om_l[co * 33 + h * 16 + g * 4 + j] = v;
                }
            }
        }
        __syncthreads();

        // om -> registers (before val_q overwrites the arena)
        int px = tid & 31;
        int dg = tid >> 5;                // 0..7

        float dy[9], dxv[9], mk[9];
#pragma unroll
        for (int k = 0; k < 9; ++k) {
            dy[k]  = om_l[(dg * 18 + 2 * k) * 33 + px];
            dxv[k] = om_l[(dg * 18 + 2 * k + 1) * 33 + px];
            mk[k]  = om_l[(C_OFF + dg * 9 + k) * 33 + px];
        }
        __syncthreads();                  // om_l reads complete; arena may be reused

        // sampling phase: taps in pairs — issue both taps' 8 loads, then interp
        const unsigned short* plane0 = inb + ((size_t)b * HW << 6) + dg * 8;
        float yb = (float)(ho - 1);
        float xb = (float)(wo0t + px - 1);

#pragma unroll
        for (int kg = 0; kg < 5; ++kg) {
            const int npair = (kg < 4) ? 2 : 1;     // taps {0,1}{2,3}{4,5}{6,7}{8}
            uv8 cc[2][4];
            float fys[2], fxs[2];
#pragma unroll
            for (int j2 = 0; j2 < 2; ++j2) {
                if (j2 < npair) {
                    int k = kg * 2 + j2;
                    float ys = dy[k] + yb + (float)(k / 3);
                    float xs = dxv[k] + xb + (float)(k % 3);
                    float y0f = floorf(ys), x0f = floorf(xs);
                    fys[j2] = ys - y0f; fxs[j2] = xs - x0f;
                    int y0 = (int)y0f, x0 = (int)x0f;
                    bool yv0 = (unsigned)y0 < (unsigned)HH;
                    bool yv1 = (unsigned)(y0 + 1) < (unsigned)HH;
                    bool xv0 = (unsigned)x0 < (unsigned)WW;
                    bool xv1 = (unsigned)(x0 + 1) < (unsigned)WW;
                    const unsigned short* pp = plane0 + (y0 * WW + x0) * 64;
                    cc[j2][0] = (yv0 && xv0) ? *(const uv8*)(pp)               : zero8;
                    cc[j2][1] = (yv0 && xv1) ? *(const uv8*)(pp + 64)          : zero8;
                    cc[j2][2] = (yv1 && xv0) ? *(const uv8*)(pp + 64 * WW)     : zero8;
                    cc[j2][3] = (yv1 && xv1) ? *(const uv8*)(pp + 64 * WW + 64): zero8;
                }
            }
#pragma unroll
            for (int j2 = 0; j2 < 2; ++j2) {
                if (j2 < npair) {
                    int k = kg * 2 + j2;
                    float fy = fys[j2], fx = fxs[j2];
                    uv8 r;
#pragma unroll
                    for (int j = 0; j < 8; ++j) {
                        float v00 = bf2f(cc[j2][0][j]), v01 = bf2f(cc[j2][1][j]);
                        float v10 = bf2f(cc[j2][2][j]), v11 = bf2f(cc[j2][3][j]);
                        float top = v00 + (v01 - v00) * fx;
                        float bot = v10 + (v11 - v10) * fx;
                        float v = top + (bot - top) * fy;
                        r[j] = f2bf(v * mk[k]);
                    }
                    *(uv8*)(val_q + (k * 8 + dg) * 256 + px * 8) = r;
                }
            }
        }
        __syncthreads();

        // dot phase
        int nh = wave >> 1;

        f32x4 dacc[2];
        dacc[0] = dacc[1] = (f32x4){0.f, 0.f, 0.f, 0.f};
#pragma unroll
        for (int s = 0; s < 18; ++s) {
            int q = s * 4 + g;
            bf16x8 a = *(const bf16x8*)(val_q + q * 256 + (h * 16 + arow) * 8);
#pragma unroll
            for (int n = 0; n < 2; ++n) {
                int co = nh * 32 + n * 16 + arow;
                bf16x8 bfr = *(const bf16x8*)(wTf2 + ((size_t)q * 64 + co) * 8);
                dacc[n] = __builtin_amdgcn_mfma_f32_16x16x32_bf16(a, bfr, dacc[n], 0, 0, 0);
            }
        }

#pragma unroll
        for (int n = 0; n < 2; ++n) {
            int co = nh * 32 + n * 16 + arow;
            float bias = b_dcn[co];
            f32x4 r;
#pragma unroll
            for (int j = 0; j < 4; ++j) r[j] = dacc[n][j] + bias;
            *(f32x4*)(out + (size_t)b * COUT * HW + (size_t)co * HW + hw0t + h * 16 + g * 4) = r;
        }
        __syncthreads();                  // dot reads done before next tile's epilogue
    }
}

// ---------------- fallback f32 kernels (if ws too small) ----------------

__global__ __launch_bounds__(256) void conv_om_kernel(
    const float* __restrict__ feature,
    const float* __restrict__ w_off, const float* __restrict__ b_off,
    const float* __restrict__ w_mask, const float* __restrict__ b_mask,
    float* __restrict__ om)
{
    int tid = threadIdx.x;
    int p = blockIdx.x * 256 + tid;
    int cg = blockIdx.y;
    int b  = p >> 14;
    int hw = p & (HW - 1);
    int ho = hw >> 7;
    int wo = hw & 127;
    int co0 = cg * 4;

    float acc[4];
    const float* wb[4];
#pragma unroll
    for (int j = 0; j < 4; ++j) {
        int co = co0 + j;
        if (co < C_OFF) { acc[j] = b_off[co];          wb[j] = w_off  + (size_t)co * 576; }
        else            { acc[j] = b_mask[co - C_OFF]; wb[j] = w_mask + (size_t)(co - C_OFF) * 576; }
    }
    const float* fb = feature + (size_t)b * CIN * HW;
    for (int ci = 0; ci < CIN; ++ci) {
        const float* fp = fb + ci * HW;
#pragma unroll
        for (int ky = 0; ky < 3; ++ky) {
            int y = ho + ky - 1;
            bool yvb = (unsigned)y < (unsigned)HH;
#pragma unroll
            for (int kx = 0; kx < 3; ++kx) {
                int x = wo + kx - 1;
                float v = (yvb && (unsigned)x < (unsigned)WW) ? fp[y * WW + x] : 0.f;
                int wi = ci * 9 + ky * 3 + kx;
#pragma unroll
                for (int j = 0; j < 4; ++j) acc[j] += v * wb[j][wi];
            }
        }
    }
    size_t obase = (size_t)b * C_OM * HW + hw;
#pragma unroll
    for (int j = 0; j < 4; ++j) {
        int co = co0 + j;
        float v = acc[j];
        if (co >= C_OFF) v = 1.f / (1.f + __expf(-v));
        om[obase + (size_t)co * HW] = v;
    }
}

__global__ __launch_bounds__(256) void dcn_kernel(
    const float* __restrict__ input,
    const float* __restrict__ om,
    const float* __restrict__ wT,
    const float* __restrict__ b_dcn,
    float* __restrict__ out)
{
    __shared__ float om_l[C_OM * 16];
    __shared__ float val_l[KTOT * 16];

    int tid  = threadIdx.x;
    int tile = blockIdx.x;
    int b    = tile >> 10;
    int hw0  = (tile & 1023) << 4;
    int ho   = hw0 >> 7;
    int wo0  = hw0 & 127;

    const float* omg = om + (size_t)b * C_OM * HW + hw0;
    for (int i = tid; i < C_OM * 16; i += 256) {
        int ch = i >> 4, px = i & 15;
        om_l[i] = omg[(size_t)ch * HW + px];
    }
    __syncthreads();

    for (int pair = tid; pair < 1024; pair += 256) {
        int px = pair & 15, c = pair >> 4;
        int dg = c >> 3;
        const float* plane = input + (size_t)(b * CIN + c) * HW;
        float yb = (float)(ho - 1);
        float xb = (float)(wo0 + px - 1);
#pragma unroll
        for (int k = 0; k < 9; ++k) {
            float dyv = om_l[(dg * 18 + 2 * k) * 16 + px];
            float dxv = om_l[(dg * 18 + 2 * k + 1) * 16 + px];
            float m  = om_l[(C_OFF + dg * 9 + k) * 16 + px];
            float ys = dyv + yb + (float)(k / 3);
            float xs = dxv + xb + (float)(k % 3);
            float y0f = floorf(ys), x0f = floorf(xs);
            float wy = ys - y0f, wx = xs - x0f;
            int y0 = (int)y0f, x0 = (int)x0f;
            bool yv0 = (unsigned)y0 < (unsigned)HH;
            bool yv1 = (unsigned)(y0 + 1) < (unsigned)HH;
            bool xv0 = (unsigned)x0 < (unsigned)WW;
            bool xv1 = (unsigned)(x0 + 1) < (unsigned)WW;
            const float* r0 = plane + y0 * WW + x0;
            float v00 = (yv0 && xv0) ? r0[0]      : 0.f;
            float v01 = (yv0 && xv1) ? r0[1]      : 0.f;
            float v10 = (yv1 && xv0) ? r0[WW]     : 0.f;
            float v11 = (yv1 && xv1) ? r0[WW + 1] : 0.f;
            float top = v00 + (v01 - v00) * wx;
            float bot = v10 + (v11 - v10) * wx;
            float v = top + (bot - top) * wy;
            val_l[(c * 9 + k) * 16 + px] = v * m;
        }
    }
    __syncthreads();

    int o2 = tid & 31;
    int ph = tid >> 5;
    int o0 = o2 * 2, px0 = ph * 2;
    float a00 = b_dcn[o0],     a01 = b_dcn[o0];
    float a10 = b_dcn[o0 + 1], a11 = b_dcn[o0 + 1];
    for (int kk = 0; kk < KTOT; ++kk) {
        float2 wv = *reinterpret_cast<const float2*>(wT + kk * 64 + o0);
        float va = val_l[kk * 16 + px0];
        float vb = val_l[kk * 16 + px0 + 1];
        a00 += wv.x * va; a01 += wv.x * vb;
        a10 += wv.y * va; a11 += wv.y * vb;
    }
    float* ob = out + (size_t)b * COUT * HW + hw0;
    ob[(size_t)o0 * HW + px0]           = a00;
    ob[(size_t)o0 * HW + px0 + 1]       = a01;
    ob[(size_t)(o0 + 1) * HW + px0]     = a10;
    ob[(size_t)(o0 + 1) * HW + px0 + 1] = a11;
}

extern "C" void kernel_launch(void* const* d_in, const int* in_sizes, int n_in,
                              void* d_out, int out_size, void* d_ws, size_t ws_size,
                              hipStream_t stream) {
    const float* input   = (const float*)d_in[0];
    const float* feature = (const float*)d_in[1];
    const float* w_off   = (const float*)d_in[2];
    const float* b_off   = (const float*)d_in[3];
    const float* w_mask  = (const float*)d_in[4];
    const float* b_mask  = (const float*)d_in[5];
    const float* w_dcn   = (const float*)d_in[6];
    const float* b_dcn   = (const float*)d_in[7];
    float* out = (float*)d_out;

    // ws layout (full path): no om buffer needed
    unsigned short* fnhwc = (unsigned short*)d_ws;                   // 8.39 MB
    unsigned short* wBp   = fnhwc + (size_t)NB * HW * CIN;           // 258 KB
    unsigned short* wTfp  = wBp + (size_t)C_PAD * KTOT;              // 73.7 KB
    unsigned short* inb   = wTfp + 72 * 64 * 8;                      // 8.39 MB
    size_t need_full = (size_t)((char*)(inb + (size_t)NB * HW * CIN) - (char*)d_ws);
    // fallback needs om (56.6 MB) + wT (147 KB)
    size_t need_fb = ((size_t)NB * C_OM * HW + KTOT * COUT) * sizeof(float);

    if (ws_size >= need_full) {
        to_nhwc_bf16_2<<<NB * HW * 2 / 256, 256, 0, stream>>>(feature, fnhwc, input, inb);
        prep_weights<<<(C_PAD * KTOT + 72 * 64 * 8 + 255) / 256, 256, 0, stream>>>(
            w_off, w_mask, w_dcn, wBp, wTfp);
        dcn_fused<<<NB * HW / 64, 256, 0, stream>>>(fnhwc, inb, wBp, wTfp,
                                                    b_off, b_mask, b_dcn, out);
    } else if (ws_size >= need_fb) {
        // fallback: pure f32 path (R1-validated)
        float* om = (float*)d_ws;
        float* wT = om + (size_t)NB * C_OM * HW;
        transpose_wdcn<<<(KTOT * COUT + 255) / 256, 256, 0, stream>>>(w_dcn, wT);
        dim3 cgrid(NB * HW / 256, 54);
        conv_om_kernel<<<cgrid, 256, 0, stream>>>(feature, w_off, b_off, w_mask, b_mask, om);
        dcn_kernel<<<NB * HW / 16, 256, 0, stream>>>(input, om, wT, b_dcn, out);
    }
}

// Round 18
// 82.087 us; speedup vs baseline: 1.0421x; 1.0373x over previous
//
#include <hip/hip_runtime.h>
#include <hip/hip_bf16.h>

#define NB 4
#define CIN 64
#define COUT 64
#define HH 128
#define WW 128
#define HW (HH*WW)
#define C_OFF 144
#define C_OM 216
#define C_PAD 224
#define KTOT 576   // CIN * 9

typedef __attribute__((ext_vector_type(8))) short bf16x8;
typedef __attribute__((ext_vector_type(4))) float f32x4;
typedef __attribute__((ext_vector_type(8))) unsigned short uv8;

__device__ inline unsigned short f2bf(float f) {
    union { float f; unsigned u; } v; v.f = f;
    unsigned r = (v.u + 0x7FFF + ((v.u >> 16) & 1)) >> 16;   // RNE
    return (unsigned short)r;
}

__device__ inline float bf2f(unsigned short h) {
    union { unsigned u; float f; } v; v.u = ((unsigned)h) << 16; return v.f;
}

// ---------------- single merged prep kernel ----------------
// Work items 0..131071: NHWC bf16 transpose of feature (0..65535) and input
// (65536..131071) — verbatim to_nhwc_bf16_2 logic. Work items 131072..296959:
// weight packing (wB then wTf2) — verbatim prep_weights formulas.

#define N_NHWC (2 * NB * HW)                       // 131072
#define N_WB   (C_PAD * KTOT)                      // 129024
#define N_WT   (72 * 64 * 8)                       // 36864
#define N_PREP (N_NHWC + N_WB + N_WT)              // 296960

__global__ __launch_bounds__(256) void prep_all(const float* __restrict__ feature,
                                                unsigned short* __restrict__ fnhwc,
                                                const float* __restrict__ input,
                                                unsigned short* __restrict__ inb,
                                                const float* __restrict__ w_off,
                                                const float* __restrict__ w_mask,
                                                const float* __restrict__ w_dcn,
                                                unsigned short* __restrict__ wB,
                                                unsigned short* __restrict__ wTf2) {
    int t = blockIdx.x * 256 + threadIdx.x;
    if (t < N_NHWC) {
        int tt = t & 65535;
        int b = tt >> 14, yx = tt & 16383;
        const float* src;
        unsigned short* dst;
        if (t < 65536) { src = feature + (size_t)b * CIN * HW + yx; dst = fnhwc + (size_t)tt * 64; }
        else           { src = input   + (size_t)b * CIN * HW + yx; dst = inb   + (size_t)tt * 64; }
#pragma unroll
        for (int c8 = 0; c8 < 8; ++c8) {
            uv8 v;
#pragma unroll
            for (int j = 0; j < 8; ++j) v[j] = f2bf(src[(size_t)(c8 * 8 + j) * HW]);
            *(uv8*)(dst + c8 * 8) = v;
        }
    } else if (t < N_NHWC + N_WB) {
        int idx = t - N_NHWC;
        int co = idx / KTOT, k = idx - co * KTOT;
        int tp = k >> 6, ci = k & 63;
        float v = 0.f;
        if (co < C_OFF)      v = w_off[(size_t)co * KTOT + ci * 9 + tp];
        else if (co < C_OM)  v = w_mask[(size_t)(co - C_OFF) * KTOT + ci * 9 + tp];
        wB[idx] = f2bf(v);
    } else if (t < N_PREP) {
        int j = t - N_NHWC - N_WB;
        int q = j >> 9;
        int co = (j >> 3) & 63;
        int r = j & 7;
        int k = q >> 3, dg = q & 7;
        wTf2[j] = f2bf(w_dcn[(size_t)co * KTOT + (dg * 8 + r) * 9 + k]);
    }
}

// ---------------- fused: conv(B-reuse supertile) -> om_l -> sampling -> dot ----------------
// R15-validated kernel, byte-identical (best known: 84.4us). 64-px supertile =
// two 32-px tiles sharing one staged B tile; XCD-aware bijective block swizzle;
// arena-aliasing discipline conv(Ash0+Ash1+Bsh) -> om_l -> val_q.

__global__ __launch_bounds__(256, 4) void dcn_fused(
    const unsigned short* __restrict__ fnhwc,  // feature NHWC bf16
    const unsigned short* __restrict__ inb,    // input NHWC bf16
    const unsigned short* __restrict__ wB,     // [224][576] bf16
    const unsigned short* __restrict__ wTf2,   // [72][64][8] bf16
    const float* __restrict__ b_off, const float* __restrict__ b_mask,
    const float* __restrict__ b_dcn,
    float* __restrict__ out)
{
    __shared__ __align__(16) unsigned char smem[36864];   // arena
    unsigned short* Ash0  = (unsigned short*)smem;              // [0,4096)
    unsigned short* Ash1  = (unsigned short*)(smem + 4096);     // [4096,8192)
    unsigned short* Bsh   = (unsigned short*)(smem + 8192);     // [8192,36864)
    float* om_l           = (float*)smem;                       // [0,29568)
    unsigned short* val_q = (unsigned short*)smem;              // [0,36864)

    int tid = threadIdx.x;
    int bid0 = blockIdx.x;                // 1024
    int bid  = ((bid0 & 7) << 7) + (bid0 >> 3);   // T1: XCD gets 128 consecutive supertiles
    int b   = bid >> 8;
    int hw0 = (bid & 255) << 6;           // 64-px supertile, row-aligned
    int ho  = hw0 >> 7;
    int wo0 = hw0 & 127;                  // 0 or 64

    int lane = tid & 63, wave = tid >> 6;
    int arow = lane & 15, g = lane >> 4;
    int h  = wave & 1;                    // px 16-half within 32-px tile
    int ws = wave >> 1;                   // co 112-half

    // ---- conv phase ----
    f32x4 acc0[7], acc1[7];
#pragma unroll
    for (int n = 0; n < 7; ++n) {
        acc0[n] = (f32x4){0.f, 0.f, 0.f, 0.f};
        acc1[n] = (f32x4){0.f, 0.f, 0.f, 0.f};
    }

    int px_w = tid >> 3;                  // 0..31
    int c8_w = tid & 7;
    const uv8 zero8 = (uv8){0, 0, 0, 0, 0, 0, 0, 0};

    for (int t = 0; t < 9; ++t) {
        int ky = t / 3, kx = t - ky * 3;
        int y = ho + ky - 1;
        bool yv = (unsigned)y < (unsigned)HH;
        __syncthreads();
        // stage A for both px tiles (R10 swizzle)
#pragma unroll
        for (int pt = 0; pt < 2; ++pt) {
            int x = wo0 + pt * 32 + px_w + kx - 1;
            uv8 v = zero8;
            if (yv && (unsigned)x < (unsigned)WW)
                v = *(const uv8*)(fnhwc + ((size_t)((b * HH + y) * WW + x) << 6) + c8_w * 8);
            int off16 = (c8_w << 4) ^ ((px_w & 7) << 4);
            char* dst = (char*)(pt ? Ash1 : Ash0);
            *(uv8*)(dst + px_w * 128 + off16) = v;
        }
        // stage B tile for this tap (R10 swizzle), shared by both px tiles
#pragma unroll
        for (int r = 0; r < 7; ++r) {
            int idx = r * 256 + tid;      // 0..1791 = 224*8 chunks
            int co = idx >> 3, c8 = idx & 7;
            uv8 v = *(const uv8*)(wB + (size_t)co * KTOT + t * 64 + c8 * 8);
            *(uv8*)((char*)Bsh + co * 128 + ((c8 << 4) ^ ((co & 7) << 4))) = v;
        }
        __syncthreads();
#pragma unroll
        for (int half = 0; half < 2; ++half) {
            int px = h * 16 + arow;
            int kb = half * 64 + g * 16;
            bf16x8 a0 = *(const bf16x8*)((const char*)Ash0 + px * 128 + (kb ^ ((px & 7) << 4)));
            bf16x8 a1 = *(const bf16x8*)((const char*)Ash1 + px * 128 + (kb ^ ((px & 7) << 4)));
#pragma unroll
            for (int n = 0; n < 7; ++n) {
                int co = ws * 112 + n * 16 + arow;   // co&7 == arow&7
                bf16x8 bf = *(const bf16x8*)((const char*)Bsh + co * 128 +
                                             (kb ^ ((co & 7) << 4)));
                acc0[n] = __builtin_amdgcn_mfma_f32_16x16x32_bf16(a0, bf, acc0[n], 0, 0, 0);
                acc1[n] = __builtin_amdgcn_mfma_f32_16x16x32_bf16(a1, bf, acc1[n], 0, 0, 0);
            }
        }
    }
    __syncthreads();   // all Ash/Bsh reads done before om_l overwrites the arena

    // ---- post-conv phases, per 32-px tile ----
#pragma unroll
    for (int pt = 0; pt < 2; ++pt) {
        int hw0t = hw0 + pt * 32;
        int wo0t = wo0 + pt * 32;

        // conv epilogue -> om_l (bias + sigmoid for mask channels)
#pragma unroll
        for (int n = 0; n < 7; ++n) {
            int co = ws * 112 + n * 16 + arow;
            if (co < C_OM) {
                float bias = (co < C_OFF) ? b_off[co] : b_mask[co - C_OFF];
                f32x4 av = pt ? acc1[n] : acc0[n];
#pragma unroll
                for (int j = 0; j < 4; ++j) {
                    float v = av[j] + bias;
                    if (co >= C_OFF) v = 1.f / (1.f + __expf(-v));
                    om_l[co * 33 + h * 16 + g * 4 + j] = v;
                }
            }
        }
        __syncthreads();

        // om -> registers (before val_q overwrites the arena)
        int px = tid & 31;
        int dg = tid >> 5;                // 0..7

        float dy[9], dxv[9], mk[9];
#pragma unroll
        for (int k = 0; k < 9; ++k) {
            dy[k]  = om_l[(dg * 18 + 2 * k) * 33 + px];
            dxv[k] = om_l[(dg * 18 + 2 * k + 1) * 33 + px];
            mk[k]  = om_l[(C_OFF + dg * 9 + k) * 33 + px];
        }
        __syncthreads();                  // om_l reads complete; arena may be reused

        // sampling phase
        const unsigned short* plane0 = inb + ((size_t)b * HW << 6) + dg * 8;
        float yb = (float)(ho - 1);
        float xb = (float)(wo0t + px - 1);

#pragma unroll
        for (int k = 0; k < 9; ++k) {
            float ys = dy[k] + yb + (float)(k / 3);
            float xs = dxv[k] + xb + (float)(k % 3);
            float y0f = floorf(ys), x0f = floorf(xs);
            float fy = ys - y0f, fx = xs - x0f;
            int y0 = (int)y0f, x0 = (int)x0f;
            bool yv0 = (unsigned)y0 < (unsigned)HH;
            bool yv1 = (unsigned)(y0 + 1) < (unsigned)HH;
            bool xv0 = (unsigned)x0 < (unsigned)WW;
            bool xv1 = (unsigned)(x0 + 1) < (unsigned)WW;
            const unsigned short* pp = plane0 + (y0 * WW + x0) * 64;
            uv8 c00 = zero8, c01 = zero8, c10 = zero8, c11 = zero8;
            if (yv0 && xv0) c00 = *(const uv8*)(pp);
            if (yv0 && xv1) c01 = *(const uv8*)(pp + 64);
            if (yv1 && xv0) c10 = *(const uv8*)(pp + 64 * WW);
            if (yv1 && xv1) c11 = *(const uv8*)(pp + 64 * WW + 64);
            uv8 r;
#pragma unroll
            for (int j = 0; j < 8; ++j) {
                float v00 = bf2f(c00[j]), v01 = bf2f(c01[j]);
                float v10 = bf2f(c10[j]), v11 = bf2f(c11[j]);
                float top = v00 + (v01 - v00) * fx;
                float bot = v10 + (v11 - v10) * fx;
                float v = top + (bot - top) * fy;
                r[j] = f2bf(v * mk[k]);
            }
            *(uv8*)(val_q + (k * 8 + dg) * 256 + px * 8) = r;
        }
        __syncthreads();

        // dot phase
        int nh = wave >> 1;

        f32x4 dacc[2];
        dacc[0] = dacc[1] = (f32x4){0.f, 0.f, 0.f, 0.f};
#pragma unroll
        for (int s = 0; s < 18; ++s) {
            int q = s * 4 + g;
            bf16x8 a = *(const bf16x8*)(val_q + q * 256 + (h * 16 + arow) * 8);
#pragma unroll
            for (int n = 0; n < 2; ++n) {
                int co = nh * 32 + n * 16 + arow;
                bf16x8 bfr = *(const bf16x8*)(wTf2 + ((size_t)q * 64 + co) * 8);
                dacc[n] = __builtin_amdgcn_mfma_f32_16x16x32_bf16(a, bfr, dacc[n], 0, 0, 0);
            }
        }

#pragma unroll
        for (int n = 0; n < 2; ++n) {
            int co = nh * 32 + n * 16 + arow;
            float bias = b_dcn[co];
            f32x4 r;
#pragma unroll
            for (int j = 0; j < 4; ++j) r[j] = dacc[n][j] + bias;
            *(f32x4*)(out + (size_t)b * COUT * HW + (size_t)co * HW + hw0t + h * 16 + g * 4) = r;
        }
        __syncthreads();                  // dot reads done before next tile's epilogue
    }
}

// ---------------- fallback f32 kernels (if ws too small) ----------------

__global__ __launch_bounds__(256) void transpose_wdcn(const float* __restrict__ w,
                                                      float* __restrict__ wT) {
    int idx = blockIdx.x * 256 + threadIdx.x;
    if (idx < KTOT * COUT) {
        int o = idx & 63, kk = idx >> 6;
        wT[idx] = w[o * KTOT + kk];
    }
}

__global__ __launch_bounds__(256) void conv_om_kernel(
    const float* __restrict__ feature,
    const float* __restrict__ w_off, const float* __restrict__ b_off,
    const float* __restrict__ w_mask, const float* __restrict__ b_mask,
    float* __restrict__ om)
{
    int tid = threadIdx.x;
    int p = blockIdx.x * 256 + tid;
    int cg = blockIdx.y;
    int b  = p >> 14;
    int hw = p & (HW - 1);
    int ho = hw >> 7;
    int wo = hw & 127;
    int co0 = cg * 4;

    float acc[4];
    const float* wb[4];
#pragma unroll
    for (int j = 0; j < 4; ++j) {
        int co = co0 + j;
        if (co < C_OFF) { acc[j] = b_off[co];          wb[j] = w_off  + (size_t)co * 576; }
        else            { acc[j] = b_mask[co - C_OFF]; wb[j] = w_mask + (size_t)(co - C_OFF) * 576; }
    }
    const float* fb = feature + (size_t)b * CIN * HW;
    for (int ci = 0; ci < CIN; ++ci) {
        const float* fp = fb + ci * HW;
#pragma unroll
        for (int ky = 0; ky < 3; ++ky) {
            int y = ho + ky - 1;
            bool yvb = (unsigned)y < (unsigned)HH;
#pragma unroll
            for (int kx = 0; kx < 3; ++kx) {
                int x = wo + kx - 1;
                float v = (yvb && (unsigned)x < (unsigned)WW) ? fp[y * WW + x] : 0.f;
                int wi = ci * 9 + ky * 3 + kx;
#pragma unroll
                for (int j = 0; j < 4; ++j) acc[j] += v * wb[j][wi];
            }
        }
    }
    size_t obase = (size_t)b * C_OM * HW + hw;
#pragma unroll
    for (int j = 0; j < 4; ++j) {
        int co = co0 + j;
        float v = acc[j];
        if (co >= C_OFF) v = 1.f / (1.f + __expf(-v));
        om[obase + (size_t)co * HW] = v;
    }
}

__global__ __launch_bounds__(256) void dcn_kernel(
    const float* __restrict__ input,
    const float* __restrict__ om,
    const float* __restrict__ wT,
    const float* __restrict__ b_dcn,
    float* __restrict__ out)
{
    __shared__ float om_l[C_OM * 16];
    __shared__ float val_l[KTOT * 16];

    int tid  = threadIdx.x;
    int tile = blockIdx.x;
    int b    = tile >> 10;
    int hw0  = (tile & 1023) << 4;
    int ho   = hw0 >> 7;
    int wo0  = hw0 & 127;

    const float* omg = om + (size_t)b * C_OM * HW + hw0;
    for (int i = tid; i < C_OM * 16; i += 256) {
        int ch = i >> 4, px = i & 15;
        om_l[i] = omg[(size_t)ch * HW + px];
    }
    __syncthreads();

    for (int pair = tid; pair < 1024; pair += 256) {
        int px = pair & 15, c = pair >> 4;
        int dg = c >> 3;
        const float* plane = input + (size_t)(b * CIN + c) * HW;
        float yb = (float)(ho - 1);
        float xb = (float)(wo0 + px - 1);
#pragma unroll
        for (int k = 0; k < 9; ++k) {
            float dyv = om_l[(dg * 18 + 2 * k) * 16 + px];
            float dxv = om_l[(dg * 18 + 2 * k + 1) * 16 + px];
            float m  = om_l[(C_OFF + dg * 9 + k) * 16 + px];
            float ys = dyv + yb + (float)(k / 3);
            float xs = dxv + xb + (float)(k % 3);
            float y0f = floorf(ys), x0f = floorf(xs);
            float wy = ys - y0f, wx = xs - x0f;
            int y0 = (int)y0f, x0 = (int)x0f;
            bool yv0 = (unsigned)y0 < (unsigned)HH;
            bool yv1 = (unsigned)(y0 + 1) < (unsigned)HH;
            bool xv0 = (unsigned)x0 < (unsigned)WW;
            bool xv1 = (unsigned)(x0 + 1) < (unsigned)WW;
            const float* r0 = plane + y0 * WW + x0;
            float v00 = (yv0 && xv0) ? r0[0]      : 0.f;
            float v01 = (yv0 && xv1) ? r0[1]      : 0.f;
            float v10 = (yv1 && xv0) ? r0[WW]     : 0.f;
            float v11 = (yv1 && xv1) ? r0[WW + 1] : 0.f;
            float top = v00 + (v01 - v00) * wx;
            float bot = v10 + (v11 - v10) * wx;
            float v = top + (bot - top) * wy;
            val_l[(c * 9 + k) * 16 + px] = v * m;
        }
    }
    __syncthreads();

    int o2 = tid & 31;
    int ph = tid >> 5;
    int o0 = o2 * 2, px0 = ph * 2;
    float a00 = b_dcn[o0],     a01 = b_dcn[o0];
    float a10 = b_dcn[o0 + 1], a11 = b_dcn[o0 + 1];
    for (int kk = 0; kk < KTOT; ++kk) {
        float2 wv = *reinterpret_cast<const float2*>(wT + kk * 64 + o0);
        float va = val_l[kk * 16 + px0];
        float vb = val_l[kk * 16 + px0 + 1];
        a00 += wv.x * va; a01 += wv.x * vb;
        a10 += wv.y * va; a11 += wv.y * vb;
    }
    float* ob = out + (size_t)b * COUT * HW + hw0;
    ob[(size_t)o0 * HW + px0]           = a00;
    ob[(size_t)o0 * HW + px0 + 1]       = a01;
    ob[(size_t)(o0 + 1) * HW + px0]     = a10;
    ob[(size_t)(o0 + 1) * HW + px0 + 1] = a11;
}

extern "C" void kernel_launch(void* const* d_in, const int* in_sizes, int n_in,
                              void* d_out, int out_size, void* d_ws, size_t ws_size,
                              hipStream_t stream) {
    const float* input   = (const float*)d_in[0];
    const float* feature = (const float*)d_in[1];
    const float* w_off   = (const float*)d_in[2];
    const float* b_off   = (const float*)d_in[3];
    const float* w_mask  = (const float*)d_in[4];
    const float* b_mask  = (const float*)d_in[5];
    const float* w_dcn   = (const float*)d_in[6];
    const float* b_dcn   = (const float*)d_in[7];
    float* out = (float*)d_out;

    // ws layout (full path): no om buffer needed
    unsigned short* fnhwc = (unsigned short*)d_ws;                   // 8.39 MB
    unsigned short* wBp   = fnhwc + (size_t)NB * HW * CIN;           // 258 KB
    unsigned short* wTfp  = wBp + (size_t)C_PAD * KTOT;              // 73.7 KB
    unsigned short* inb   = wTfp + 72 * 64 * 8;                      // 8.39 MB
    size_t need_full = (size_t)((char*)(inb + (size_t)NB * HW * CIN) - (char*)d_ws);
    // fallback needs om (56.6 MB) + wT (147 KB)
    size_t need_fb = ((size_t)NB * C_OM * HW + KTOT * COUT) * sizeof(float);

    if (ws_size >= need_full) {
        prep_all<<<(N_PREP + 255) / 256, 256, 0, stream>>>(
            feature, fnhwc, input, inb, w_off, w_mask, w_dcn, wBp, wTfp);
        dcn_fused<<<NB * HW / 64, 256, 0, stream>>>(fnhwc, inb, wBp, wTfp,
                                                    b_off, b_mask, b_dcn, out);
    } else if (ws_size >= need_fb) {
        // fallback: pure f32 path (R1-validated)
        float* om = (float*)d_ws;
        float* wT = om + (size_t)NB * C_OM * HW;
        transpose_wdcn<<<(KTOT * COUT + 255) / 256, 256, 0, stream>>>(w_dcn, wT);
        dim3 cgrid(NB * HW / 256, 54);
        conv_om_kernel<<<cgrid, 256, 0, stream>>>(feature, w_off, b_off, w_mask, b_mask, om);
        dcn_kernel<<<NB * HW / 16, 256, 0, stream>>>(input, om, wT, b_dcn, out);
    }
}